// Round 8
// baseline (562.844 us; speedup 1.0000x reference)
//
#include <hip/hip_runtime.h>
#include <hip/hip_bf16.h>
#include <cstdint>
#include <cstddef>

using bf16 = __hip_bfloat16;

typedef __attribute__((ext_vector_type(4))) float f32x4;
typedef __attribute__((ext_vector_type(8))) short s16x8;

#define LSEQ 4096
#define DDIM 512
#define KFLT 24
#define NFFT 8192
#define MR 8192              // 2*4096 interleaved re/im rows (Nyquist handled rank-1)

__device__ __forceinline__ void gld16(const bf16* g, bf16* l) {
  __builtin_amdgcn_global_load_lds((const __attribute__((address_space(1))) void*)g,
                                   (__attribute__((address_space(3))) void*)l, 16, 0, 0);
}

#define MEMFENCE asm volatile("" ::: "memory")
#define BAR() do { MEMFENCE; __builtin_amdgcn_s_barrier(); MEMFENCE; } while (0)

__device__ __forceinline__ float fsin_rev(float rev) {
  float s; asm("v_sin_f32 %0, %1" : "=v"(s) : "v"(rev)); return s;
}
__device__ __forceinline__ float fcos_rev(float rev) {
  float c; asm("v_cos_f32 %0, %1" : "=v"(c) : "v"(rev)); return c;
}

// Stage one 128x64 bf16 half-tile global->LDS, pre-swizzled source (slot ^= row&7)
__device__ __forceinline__ void stage_half(const bf16* g, int ldk, bf16* ldsbase,
                                           int wave, int lane) {
  const int r8 = lane >> 3;
  const int sc = ((lane & 7) ^ r8) * 8;
  #pragma unroll
  for (int q = 0; q < 2; ++q) {
    const int c = wave * 2 + q;
    gld16(g + (size_t)(c * 8 + r8) * ldk + sc, ldsbase + c * 512);
  }
}

// swizzled LDS fragment read: 16B at slot (kk*4+l4)^(row&7)
__device__ __forceinline__ s16x8 ldfrag(const bf16* buf, int row, int kk, int l4) {
  return *(const s16x8*)(buf + row * 64 + (((kk * 4 + l4) ^ (row & 7)) * 8));
}

// -------- transpose + cast->bf16: out[c][r] = bf16(in[r][c]), batched over z
__global__ __launch_bounds__(256) void transpose_cast(
    const float* __restrict__ in, bf16* __restrict__ out, int R, int C) {
  __shared__ float tile[32][33];
  const size_t bo = (size_t)blockIdx.z * R * C;
  const float* inb = in + bo;
  bf16* outb = out + bo;
  int c0 = blockIdx.x * 32, r0 = blockIdx.y * 32;
  int tx = threadIdx.x & 31, ty = threadIdx.x >> 5;
  #pragma unroll
  for (int i = 0; i < 32; i += 8)
    tile[ty + i][tx] = inb[(size_t)(r0 + ty + i) * C + (c0 + tx)];
  __syncthreads();
  #pragma unroll
  for (int i = 0; i < 32; i += 8)
    outb[(size_t)(c0 + ty + i) * R + (r0 + tx)] = __float2bfloat16(tile[tx][ty + i]);
}

// -------- Auf = bf16(P0 + P1) (two bf16 half-K partials)
__global__ __launch_bounds__(256) void add2_cast(
    const bf16* __restrict__ P, bf16* __restrict__ out) {
  size_t i = ((size_t)blockIdx.x * 256 + threadIdx.x) * 8;
  const size_t MN = (size_t)MR * DDIM;
  s16x8 a = *(const s16x8*)(P + i);
  s16x8 b = *(const s16x8*)(P + i + MN);
  bf16 o[8];
  #pragma unroll
  for (int e = 0; e < 8; ++e) {
    float fa = __uint_as_float((unsigned)(unsigned short)a[e] << 16);
    float fb = __uint_as_float((unsigned)(unsigned short)b[e] << 16);
    o[e] = __float2bfloat16(fa + fb);
  }
  *(s16x8*)(out + i) = *(const s16x8*)o;
}

// -------- Ybt[c][r] = bf16(sum_jg Slot[(jg,nt(c))][r][c&255]); slots [8192][256] f32
__global__ __launch_bounds__(256) void tr_reduce4(
    const float* __restrict__ S, bf16* __restrict__ out) {
  __shared__ float tile[32][33];
  int c0 = blockIdx.x * 32, r0 = blockIdx.y * 32;
  int tx = threadIdx.x & 31, ty = threadIdx.x >> 5;
  const int nt = c0 >> 8;
  const int scl = (c0 & 255) + tx;
  const size_t SB = (size_t)MR * 256;
  #pragma unroll
  for (int i = 0; i < 32; i += 8) {
    size_t ro = (size_t)(r0 + ty + i) * 256 + scl;
    tile[ty + i][tx] = S[(0 * 2 + nt) * SB + ro] + S[(1 * 2 + nt) * SB + ro] +
                       S[(2 * 2 + nt) * SB + ro] + S[(3 * 2 + nt) * SB + ro];
  }
  __syncthreads();
  #pragma unroll
  for (int i = 0; i < 32; i += 8)
    out[(size_t)(c0 + ty + i) * MR + (r0 + tx)] = __float2bfloat16(tile[tx][ty + i]);
}

// -------- y = sum of 4 f32 partials + (-1)^l * vnyq[o] / NFFT
__global__ __launch_bounds__(256) void reduce4y(
    const float* __restrict__ P, const float* __restrict__ vnyq,
    float* __restrict__ y) {
  size_t i = ((size_t)blockIdx.x * 256 + threadIdx.x) * 4;
  const size_t MN = (size_t)LSEQ * DDIM;
  int l = (int)(i >> 9), o = (int)(i & 511);
  f32x4 a = *(const f32x4*)(P + i);
  f32x4 b = *(const f32x4*)(P + i + MN);
  f32x4 c = *(const f32x4*)(P + i + 2 * MN);
  f32x4 d = *(const f32x4*)(P + i + 3 * MN);
  f32x4 v = *(const f32x4*)(vnyq + o);
  float sg = (l & 1) ? -(1.f / NFFT) : (1.f / NFFT);
  f32x4 r = a + b + c + d;
  r[0] += sg * v[0]; r[1] += sg * v[1]; r[2] += sg * v[2]; r[3] += sg * v[3];
  *(f32x4*)(y + i) = r;
}

// -------- forward-DFT matrix rows 0..8191: W[2f][t]=cos, W[2f+1][t]=-sin
__global__ __launch_bounds__(256) void gen_w(bf16* __restrict__ W) {
  int r = blockIdx.y;
  int t0 = (blockIdx.x * 256 + threadIdx.x) * 8;
  int f = r >> 1;
  bool odd = r & 1;
  bf16 o[8];
  #pragma unroll
  for (int i = 0; i < 8; ++i) {
    int m = (f * (t0 + i)) & (NFFT - 1);
    float rev = (float)m * (1.f / NFFT);
    float v = odd ? -fsin_rev(rev) : fcos_rev(rev);
    o[i] = __float2bfloat16(v);
  }
  *(s16x8*)(W + (size_t)r * LSEQ + t0) = *(const s16x8*)o;
}

// -------- inverse-DFT matrix [4096][8192]: Cinv[l][2f]=wf/N*cos, [2f+1]=-wf/N*sin
__global__ __launch_bounds__(256) void gen_cinv(bf16* __restrict__ Cinv) {
  int l = blockIdx.y;
  int r0 = (blockIdx.x * 256 + threadIdx.x) * 8;
  bf16 o[8];
  #pragma unroll
  for (int p = 0; p < 4; ++p) {
    int f = (r0 >> 1) + p;
    int m = (f * l) & (NFFT - 1);
    float rev = (float)m * (1.f / NFFT);
    float sc = ((f == 0) ? 1.f : 2.f) * (1.f / NFFT);
    o[2 * p] = __float2bfloat16(sc * fcos_rev(rev));
    o[2 * p + 1] = __float2bfloat16(-sc * fsin_rev(rev));
  }
  *(s16x8*)(Cinv + (size_t)l * MR + r0) = *(const s16x8*)o;
}

// -------- Pf[f][k][re,im] f32, f in [0,4096]; 2 f per block (phi reads amortized)
__global__ __launch_bounds__(256) void compute_pf(
    const float* __restrict__ phi, float* __restrict__ Pf) {
  int f0 = blockIdx.x * 2;
  int tid = threadIdx.x;
  int lane = tid & 63, wave = tid >> 6;
  float pre[2][KFLT], pim[2][KFLT];
  #pragma unroll
  for (int ff = 0; ff < 2; ++ff)
    #pragma unroll
    for (int k = 0; k < KFLT; ++k) { pre[ff][k] = 0.f; pim[ff][k] = 0.f; }
  for (int cch = 0; cch < LSEQ / 256; ++cch) {
    int t = cch * 256 + tid;
    const float4* pv = (const float4*)(phi + (size_t)t * KFLT);
    float4 v0 = pv[0], v1 = pv[1], v2 = pv[2], v3 = pv[3], v4 = pv[4], v5 = pv[5];
    float pr[KFLT] = {v0.x, v0.y, v0.z, v0.w, v1.x, v1.y, v1.z, v1.w,
                      v2.x, v2.y, v2.z, v2.w, v3.x, v3.y, v3.z, v3.w,
                      v4.x, v4.y, v4.z, v4.w, v5.x, v5.y, v5.z, v5.w};
    #pragma unroll
    for (int ff = 0; ff < 2; ++ff) {
      int m = ((f0 + ff) * t) & (NFFT - 1);
      float rev = (float)m * (1.f / NFFT);
      float s = fsin_rev(rev), c = fcos_rev(rev);
      #pragma unroll
      for (int k = 0; k < KFLT; ++k) {
        pre[ff][k] += pr[k] * c;
        pim[ff][k] -= pr[k] * s;
      }
    }
  }
  __shared__ float red[4][2][2 * KFLT];
  #pragma unroll
  for (int ff = 0; ff < 2; ++ff)
    #pragma unroll
    for (int k = 0; k < KFLT; ++k) {
      float r = pre[ff][k], i2 = pim[ff][k];
      #pragma unroll
      for (int off = 32; off > 0; off >>= 1) {
        r += __shfl_down(r, off, 64);
        i2 += __shfl_down(i2, off, 64);
      }
      if (lane == 0) { red[wave][ff][2 * k] = r; red[wave][ff][2 * k + 1] = i2; }
    }
  __syncthreads();
  if (tid < 96) {
    int ff = tid / 48, q = tid % 48;
    int f = f0 + ff;
    if (f <= NFFT / 2)
      Pf[(size_t)f * 48 + q] =
          red[0][ff][q] + red[1][ff][q] + red[2][ff][q] + red[3][ff][q];
  }
}

// -------- Pw[j][f][re,im], f in [0,4096); also wnyq[48]
__global__ __launch_bounds__(256) void build_pw(
    const float* __restrict__ Pf, float* __restrict__ Pw, float* __restrict__ wnyq) {
  int idx = blockIdx.x * 256 + threadIdx.x;
  int j = idx >> 12, f = idx & 4095;
  float re, im;
  if (j < KFLT) {
    re = Pf[(size_t)f * 48 + j * 2];
    im = Pf[(size_t)f * 48 + j * 2 + 1];
  } else {
    int k = j - KFLT, g = NFFT / 2 - f;
    re = Pf[(size_t)g * 48 + k * 2];
    im = -Pf[(size_t)g * 48 + k * 2 + 1];
  }
  Pw[(size_t)idx * 2] = re;
  Pw[(size_t)idx * 2 + 1] = im;
  if (idx < 48)
    wnyq[idx] = (idx < KFLT) ? Pf[(size_t)(NFFT / 2) * 48 + idx * 2]
                             : Pf[(idx - KFLT) * 2];
}

// -------- Unyq[d] += partial sum_t (-1)^t u[t][d]  (coalesced, 128 blocks)
__global__ __launch_bounds__(256) void nyq_u(
    const float* __restrict__ u, float* __restrict__ Unyq) {
  int d = blockIdx.x * 256 + threadIdx.x;
  int t0 = blockIdx.y * 64;
  float acc = 0.f;
  for (int t = t0; t < t0 + 64; t += 2)
    acc += u[(size_t)t * DDIM + d] - u[(size_t)(t + 1) * DDIM + d];
  atomicAdd(&Unyq[d], acc);
}

// -------- vnyq[o] += wnyq[j] * sum_d Unyq[d]*Mt[j][o][d]   (grid 48 x 4)
__global__ __launch_bounds__(256) void vnyq_k(
    const bf16* __restrict__ Mt, const float* __restrict__ Unyq,
    const float* __restrict__ wnyq, float* __restrict__ vnyq) {
  __shared__ float us[DDIM];
  int j = blockIdx.x, tid = threadIdx.x;
  us[tid] = Unyq[tid];
  us[tid + 256] = Unyq[tid + 256];
  __syncthreads();
  float w = wnyq[j];
  int o = blockIdx.y * 128 + (tid >> 1);
  int dh = (tid & 1) * 256;
  const bf16* row = Mt + ((size_t)j * DDIM + o) * DDIM + dh;
  float acc = 0.f;
  for (int d0 = 0; d0 < 256; d0 += 8) {
    s16x8 v = *(const s16x8*)(row + d0);
    #pragma unroll
    for (int e = 0; e < 8; ++e)
      acc += us[dh + d0 + e] * __uint_as_float((unsigned)(unsigned short)v[e] << 16);
  }
  acc += __shfl_xor(acc, 1, 64);
  if ((tid & 1) == 0) atomicAdd(&vnyq[o], w * acc);
}

// ======== direct GEMM (G1/G3): C = A[M,K] @ Bt[N,K]^T, BM=128 BN=256 BK=64,
// 8 waves 2x4 (wave 64x64), exact-cover 256 blocks, 3-deep LDS + counted vmcnt(6).
template <int STORE>
__global__ __launch_bounds__(512, 2) void gemmD(
    const bf16* __restrict__ A, const bf16* __restrict__ Bt, int ldk,
    bf16* __restrict__ Obf, float* __restrict__ Of) {
  __shared__ bf16 sA[3 * 128 * 64];
  __shared__ bf16 sB[3 * 256 * 64];

  const int lin = blockIdx.x;
  const int wid = (lin & 7) * 32 + (lin >> 3);

  int mt, nt, kt0, nkt, ks;
  if constexpr (STORE == 0) {
    ks = wid >> 7; int rem = wid & 127; mt = rem >> 1; nt = rem & 1;
    kt0 = ks * 32; nkt = 32;
  } else {
    ks = wid >> 6; int rem = wid & 63; mt = rem >> 1; nt = rem & 1;
    kt0 = ks * 32; nkt = 32;
  }

  const int tid = threadIdx.x, lane = tid & 63, wave = tid >> 6;
  const int l15 = lane & 15, l4 = lane >> 4;
  const int wr = wave >> 2, wc = wave & 3;
  const int mtile = mt * 128, ntile = nt * 256;
  const bf16* Ab = A + (size_t)mtile * ldk;
  const bf16* Bb = Bt + (size_t)ntile * ldk;

  f32x4 acc[4][4];
  #pragma unroll
  for (int m = 0; m < 4; ++m)
    #pragma unroll
    for (int n = 0; n < 4; ++n) acc[m][n] = f32x4{0.f, 0.f, 0.f, 0.f};

  auto stage = [&](int t, int buf) {
    const size_t ko = (size_t)(kt0 + t) * 64;
    stage_half(Ab + ko, ldk, sA + buf * (128 * 64), wave, lane);
    stage_half(Bb + ko, ldk, sB + buf * (256 * 64), wave, lane);
    stage_half(Bb + (size_t)128 * ldk + ko, ldk, sB + buf * (256 * 64) + 128 * 64,
               wave, lane);
  };

  stage(0, 0);
  stage(1, 1);
  asm volatile("s_waitcnt vmcnt(6)" ::: "memory");   // tile 0 landed, tile 1 in flight
  BAR();

  for (int t = 0; t < nkt; ++t) {
    const int buf = t % 3;
    const bf16* bA = sA + buf * (128 * 64);
    const bf16* bB = sB + buf * (256 * 64);
    const bool i2 = (t + 2 < nkt);

    s16x8 afr[4][2], bfr[4][2];
    #pragma unroll
    for (int n = 0; n < 4; ++n)
      #pragma unroll
      for (int kk = 0; kk < 2; ++kk)
        bfr[n][kk] = ldfrag(bB, wc * 64 + n * 16 + l15, kk, l4);
    #pragma unroll
    for (int m = 0; m < 4; ++m)
      #pragma unroll
      for (int kk = 0; kk < 2; ++kk)
        afr[m][kk] = ldfrag(bA, wr * 64 + m * 16 + l15, kk, l4);

    if (i2) stage(t + 2, (t + 2) % 3);

    __builtin_amdgcn_s_setprio(1);
    #pragma unroll
    for (int m = 0; m < 4; ++m)
      #pragma unroll
      for (int n = 0; n < 4; ++n)
        #pragma unroll
        for (int kk = 0; kk < 2; ++kk)
          acc[m][n] = __builtin_amdgcn_mfma_f32_16x16x32_bf16(
              afr[m][kk], bfr[n][kk], acc[m][n], 0, 0, 0);
    __builtin_amdgcn_s_setprio(0);

    if (i2) { asm volatile("s_waitcnt vmcnt(6)" ::: "memory"); }
    else    { asm volatile("s_waitcnt vmcnt(0)" ::: "memory"); }
    BAR();
  }

  #pragma unroll
  for (int m = 0; m < 4; ++m)
    #pragma unroll
    for (int n = 0; n < 4; ++n)
      #pragma unroll
      for (int e = 0; e < 4; ++e) {
        int row = mtile + wr * 64 + m * 16 + l4 * 4 + e;
        int col = ntile + wc * 64 + n * 16 + l15;
        if constexpr (STORE == 0)
          Obf[(size_t)ks * MR * DDIM + (size_t)row * DDIM + col] =
              __float2bfloat16(acc[m][n][e]);
        else
          Of[(size_t)ks * LSEQ * DDIM + (size_t)row * DDIM + col] = acc[m][n][e];
      }
}

// ======== G2: Slot[(jg,nt)] = sum_{j in jg} Pw[j] .* (Auf @ Mt_j^T), pre-weighted A.
// m201-style fine-phase schedule: per unit (K-tile) 4 phases, each
// {ds-reads, stage-issue, BAR, lgkmcnt(0), setprio, 16 MFMA, setprio, BAR}.
// Counted vmcnt(10) once per unit (P2) — never 0 in steady state.
// sA 2-deep + sB 3-deep = 160KB. A-regs issued 2 units ahead (P0), written 1 ahead (P2).
struct ARegs { int4 a[4]; float2 w[2]; };

__global__ __launch_bounds__(512, 2) void gemmW(
    const bf16* __restrict__ Auf, const bf16* __restrict__ Mt,
    const float* __restrict__ Pw, float* __restrict__ Slots) {
  __shared__ bf16 sA[2 * 256 * 64];
  __shared__ bf16 sB[3 * 256 * 64];

  const int lin = blockIdx.x;
  const int wid = (lin & 7) * 32 + (lin >> 3);
  const int xcd = wid >> 5, pos = wid & 31;
  const int nt = xcd & 1, jg = xcd >> 1;
  const int mt = pos;

  const int tid = threadIdx.x, lane = tid & 63, wave = tid >> 6;
  const int l15 = lane & 15, l4 = lane >> 4;
  const int wr = wave >> 2, wc = wave & 3;          // 2x4 waves, wave 128x64
  const int r8 = lane >> 3, c8 = lane & 7;

  float* dst = Slots + (size_t)(jg * 2 + nt) * ((size_t)MR * 256);

  f32x4 acc[8][4];
  #pragma unroll
  for (int m = 0; m < 8; ++m)
    #pragma unroll
    for (int n = 0; n < 4; ++n) acc[m][n] = f32x4{0.f, 0.f, 0.f, 0.f};

  auto J  = [&](int s) { return jg * 12 + (s >> 3); };
  auto KT = [&](int s) { return s & 7; };

  // per-lane row-pair A load (4 int4 + 2 float2 = 6 vmem)
  auto issueA = [&](int j, int kt, ARegs& r) {
    #pragma unroll
    for (int q = 0; q < 2; ++q) {
      int row_e = wave * 32 + 2 * (q * 8 + r8);
      int rg = mt * 256 + row_e;
      const bf16* p = Auf + (size_t)rg * DDIM + kt * 64 + c8 * 8;
      r.a[2 * q]     = *(const int4*)p;
      r.a[2 * q + 1] = *(const int4*)(p + DDIM);
      r.w[q] = *(const float2*)(Pw + ((size_t)j * 4096 + (rg >> 1)) * 2);
    }
  };
  // complex mix + swizzled ds_write (4 x b128)
  auto writeA = [&](bf16* db, const ARegs& r) {
    #pragma unroll
    for (int q = 0; q < 2; ++q) {
      int row_e = wave * 32 + 2 * (q * 8 + r8);
      union { int4 i; unsigned short u[8]; } ae, ao;
      ae.i = r.a[2 * q]; ao.i = r.a[2 * q + 1];
      bf16 oe[8], oo[8];
      #pragma unroll
      for (int e = 0; e < 8; ++e) {
        float fe = __uint_as_float((unsigned)ae.u[e] << 16);
        float fo = __uint_as_float((unsigned)ao.u[e] << 16);
        oe[e] = __float2bfloat16(r.w[q].x * fe - r.w[q].y * fo);
        oo[e] = __float2bfloat16(r.w[q].x * fo + r.w[q].y * fe);
      }
      *(s16x8*)(db + row_e * 64 + ((c8 ^ (row_e & 7)) * 8)) = *(const s16x8*)oe;
      *(s16x8*)(db + (row_e + 1) * 64 + ((c8 ^ ((row_e + 1) & 7)) * 8)) =
          *(const s16x8*)oo;
    }
  };
  auto stageB = [&](int j, int kt, bf16* db) {
    const bf16* bb = Mt + (size_t)j * (DDIM * DDIM) + (size_t)(nt * 256) * DDIM + kt * 64;
    stage_half(bb, DDIM, db, wave, lane);
    stage_half(bb + (size_t)128 * DDIM, DDIM, db + 128 * 64, wave, lane);
  };

  ARegs rA, rB_;

  // ---- prologue: A'(0) in sA[0]; B(0),B(1) staged; A(1) regs in flight
  {
    ARegs t0;
    issueA(J(0), KT(0), t0);                          // 6 vmem
    stageB(J(0), KT(0), sB);                          // 4 gld16
    asm volatile("s_waitcnt vmcnt(4)" ::: "memory");  // A(0) regs ready
    writeA(sA, t0);
    issueA(J(1), KT(1), rA);                          // 6
    stageB(J(1), KT(1), sB + 256 * 64);               // 4
    asm volatile("s_waitcnt vmcnt(10)" ::: "memory"); // B(0) landed
    asm volatile("s_waitcnt lgkmcnt(0)" ::: "memory");
    BAR();
  }

  // Rc holds A(s+1) regs (written to LDS at P2); Rn receives A(s+2) (issued P0).
  auto unit = [&](int s, ARegs& Rc, ARegs& Rn) {
    const bf16* bA = sA + (s & 1) * (256 * 64);
    const bf16* bB = sB + (s % 3) * (256 * 64);
    const bool i2 = (s + 2 < 96);
    const bool i1 = (s + 1 < 96);

    s16x8 bfr[4][2];

    // ======== P0: bfr(8) + afr m0,m1(4); issue A(s+2) + B(s+2); 16 MFMA
    {
      s16x8 afr[2][2];
      #pragma unroll
      for (int n = 0; n < 4; ++n)
        #pragma unroll
        for (int kk = 0; kk < 2; ++kk)
          bfr[n][kk] = ldfrag(bB, wc * 64 + n * 16 + l15, kk, l4);
      #pragma unroll
      for (int i = 0; i < 2; ++i)
        #pragma unroll
        for (int kk = 0; kk < 2; ++kk)
          afr[i][kk] = ldfrag(bA, wr * 128 + i * 16 + l15, kk, l4);
      if (i2) {
        issueA(J(s + 2), KT(s + 2), Rn);
        stageB(J(s + 2), KT(s + 2), sB + ((s + 2) % 3) * (256 * 64));
      }
      BAR();
      asm volatile("s_waitcnt lgkmcnt(0)" ::: "memory");
      __builtin_amdgcn_s_setprio(1);
      #pragma unroll
      for (int i = 0; i < 2; ++i)
        #pragma unroll
        for (int n = 0; n < 4; ++n)
          #pragma unroll
          for (int kk = 0; kk < 2; ++kk)
            acc[i][n] = __builtin_amdgcn_mfma_f32_16x16x32_bf16(
                afr[i][kk], bfr[n][kk], acc[i][n], 0, 0, 0);
      __builtin_amdgcn_s_setprio(0);
      BAR();
    }

    // ======== P1: afr m2,m3; 16 MFMA
    {
      s16x8 afr[2][2];
      #pragma unroll
      for (int i = 0; i < 2; ++i)
        #pragma unroll
        for (int kk = 0; kk < 2; ++kk)
          afr[i][kk] = ldfrag(bA, wr * 128 + 32 + i * 16 + l15, kk, l4);
      BAR();
      asm volatile("s_waitcnt lgkmcnt(0)" ::: "memory");
      __builtin_amdgcn_s_setprio(1);
      #pragma unroll
      for (int i = 0; i < 2; ++i)
        #pragma unroll
        for (int n = 0; n < 4; ++n)
          #pragma unroll
          for (int kk = 0; kk < 2; ++kk)
            acc[2 + i][n] = __builtin_amdgcn_mfma_f32_16x16x32_bf16(
                afr[i][kk], bfr[n][kk], acc[2 + i][n], 0, 0, 0);
      __builtin_amdgcn_s_setprio(0);
      BAR();
    }

    // ======== P2: afr m4,m5; counted vmcnt + writeA A'(s+1); 16 MFMA
    {
      s16x8 afr[2][2];
      #pragma unroll
      for (int i = 0; i < 2; ++i)
        #pragma unroll
        for (int kk = 0; kk < 2; ++kk)
          afr[i][kk] = ldfrag(bA, wr * 128 + 64 + i * 16 + l15, kk, l4);
      if (i2)      { asm volatile("s_waitcnt vmcnt(10)" ::: "memory"); }
      else if (i1) { asm volatile("s_waitcnt vmcnt(0)" ::: "memory"); }
      if (i1) writeA(sA + ((s + 1) & 1) * (256 * 64), Rc);
      BAR();
      asm volatile("s_waitcnt lgkmcnt(0)" ::: "memory");
      __builtin_amdgcn_s_setprio(1);
      #pragma unroll
      for (int i = 0; i < 2; ++i)
        #pragma unroll
        for (int n = 0; n < 4; ++n)
          #pragma unroll
          for (int kk = 0; kk < 2; ++kk)
            acc[4 + i][n] = __builtin_amdgcn_mfma_f32_16x16x32_bf16(
                afr[i][kk], bfr[n][kk], acc[4 + i][n], 0, 0, 0);
      __builtin_amdgcn_s_setprio(0);
      BAR();
    }

    // ======== P3: afr m6,m7; 16 MFMA
    {
      s16x8 afr[2][2];
      #pragma unroll
      for (int i = 0; i < 2; ++i)
        #pragma unroll
        for (int kk = 0; kk < 2; ++kk)
          afr[i][kk] = ldfrag(bA, wr * 128 + 96 + i * 16 + l15, kk, l4);
      BAR();
      asm volatile("s_waitcnt lgkmcnt(0)" ::: "memory");
      __builtin_amdgcn_s_setprio(1);
      #pragma unroll
      for (int i = 0; i < 2; ++i)
        #pragma unroll
        for (int n = 0; n < 4; ++n)
          #pragma unroll
          for (int kk = 0; kk < 2; ++kk)
            acc[6 + i][n] = __builtin_amdgcn_mfma_f32_16x16x32_bf16(
                afr[i][kk], bfr[n][kk], acc[6 + i][n], 0, 0, 0);
      __builtin_amdgcn_s_setprio(0);
      BAR();
    }
  };

  for (int sp = 0; sp < 48; ++sp) {
    unit(2 * sp,     rA, rB_);
    unit(2 * sp + 1, rB_, rA);
  }

  // single flush into the block's private (mt, nt) slot region
  #pragma unroll
  for (int m = 0; m < 8; ++m)
    #pragma unroll
    for (int n = 0; n < 4; ++n)
      #pragma unroll
      for (int e = 0; e < 4; ++e) {
        int row = mt * 256 + wr * 128 + (m & 3) * 16 + (m >> 2) * 64 + l4 * 4 + e;
        int col = wc * 64 + n * 16 + l15;
        dst[(size_t)row * 256 + col] = acc[m][n][e];
      }
}

// ---------------- workspace layout (bytes) ----------------
#define WS_W     0ULL                    // 8192x4096 bf16 = 67,108,864 (W / G2 slots / Cinv)
#define WS_AUF   67108864ULL             // 8192x512 bf16 = 8,388,608 (later G3P start)
#define WS_UT    75497472ULL             // 512x4096 bf16 = 4,194,304
#define WS_MT    79691776ULL             // 48x512x512 bf16 = 25,165,824
#define WS_PF    104857600ULL            // 4097x48 f32
#define WS_PW    105644288ULL            // 48x4096x2 f32 = 1,572,864
#define WS_WNYQ  107217152ULL            // 48 f32
#define WS_UNYQ  107217408ULL            // 512 f32
#define WS_VNYQ  107219456ULL            // 512 f32
#define WS_YBT   107221504ULL            // 512x8192 bf16 = 8,388,608
#define WS_G1P   115610112ULL            // 2 x 8192x512 bf16 = 16,777,216
#define WS_TOTAL 132387328ULL
// G3 partials: 4 x 4096x512 f32 = 33,554,432 at WS_AUF (Auf/uT/Mt dead by G3)

extern "C" void kernel_launch(void* const* d_in, const int* in_sizes, int n_in,
                              void* d_out, int out_size, void* d_ws, size_t ws_size,
                              hipStream_t stream) {
  const float* u   = (const float*)d_in[0];   // [4096, 512]
  const float* phi = (const float*)d_in[1];   // [4096, 24]
  const float* Mp  = (const float*)d_in[2];   // [24, 512, 512]
  const float* Mm  = (const float*)d_in[3];   // [24, 512, 512]
  float* y = (float*)d_out;                   // [4096, 512]

  if (ws_size < WS_TOTAL) return;             // loud failure: output stays zero

  char* ws = (char*)d_ws;
  bf16*  W    = (bf16*)(ws + WS_W);
  float* Slots= (float*)(ws + WS_W);          // G2 slots overlay (W dead after G1)
  bf16*  Auf  = (bf16*)(ws + WS_AUF);
  bf16*  uT   = (bf16*)(ws + WS_UT);
  bf16*  Mt   = (bf16*)(ws + WS_MT);
  float* Pf   = (float*)(ws + WS_PF);
  float* Pw   = (float*)(ws + WS_PW);
  float* wny  = (float*)(ws + WS_WNYQ);
  float* Uny  = (float*)(ws + WS_UNYQ);
  float* vny  = (float*)(ws + WS_VNYQ);
  bf16*  Ybt  = (bf16*)(ws + WS_YBT);
  bf16*  G1P  = (bf16*)(ws + WS_G1P);
  float* G3P  = (float*)(ws + WS_AUF);        // G3 partials overlay

  // prologue
  transpose_cast<<<dim3(16, 128, 1), 256, 0, stream>>>(u, uT, LSEQ, DDIM);
  transpose_cast<<<dim3(16, 16, 24), 256, 0, stream>>>(Mp, Mt, DDIM, DDIM);
  transpose_cast<<<dim3(16, 16, 24), 256, 0, stream>>>(Mm, Mt + (size_t)24 * DDIM * DDIM,
                                                       DDIM, DDIM);
  gen_w<<<dim3(2, MR), 256, 0, stream>>>(W);
  compute_pf<<<dim3(2049), 256, 0, stream>>>(phi, Pf);
  build_pw<<<dim3(48 * 4096 / 256), 256, 0, stream>>>(Pf, Pw, wny);
  hipMemsetAsync(Uny, 0, DDIM * sizeof(float), stream);
  nyq_u<<<dim3(2, 64), 256, 0, stream>>>(u, Uny);

  // G1: Auf = bf16(Wdft @ u), 256 blocks, ks2 bf16 partials + add-cast
  gemmD<0><<<256, 512, 0, stream>>>(W, uT, LSEQ, G1P, nullptr);
  add2_cast<<<dim3(MR * DDIM / 2048), 256, 0, stream>>>(G1P, Auf);

  // G2: 8 XCD-combo slots in W region (full coverage, no memset)
  gemmW<<<256, 512, 0, stream>>>(Auf, Mt, Pw, Slots);

  // Ybt = bf16((sum of 4 jg-slots)^T); Nyquist vector (needs Mt) before G3
  tr_reduce4<<<dim3(16, 256), 256, 0, stream>>>(Slots, Ybt);
  hipMemsetAsync(vny, 0, DDIM * sizeof(float), stream);
  vnyq_k<<<dim3(48, 4), 256, 0, stream>>>(Mt, Uny, wny, vny);

  // G3: y = Cinv @ Ysum via 4 f32 ksplit partials + fused Nyquist rank-1 reduce
  gen_cinv<<<dim3(4, LSEQ), 256, 0, stream>>>(W);
  gemmD<1><<<256, 512, 0, stream>>>(W, Ybt, MR, nullptr, G3P);
  reduce4y<<<dim3(LSEQ * DDIM / 1024), 256, 0, stream>>>(G3P, vny, y);
}

// Round 9
// 502.512 us; speedup vs baseline: 1.1201x; 1.1201x over previous
//
#include <hip/hip_runtime.h>
#include <hip/hip_bf16.h>
#include <cstdint>
#include <cstddef>

using bf16 = __hip_bfloat16;

typedef __attribute__((ext_vector_type(4))) float f32x4;
typedef __attribute__((ext_vector_type(8))) short s16x8;

#define LSEQ 4096
#define DDIM 512
#define KFLT 24
#define NFFT 8192
#define MR 8192              // 2*4096 interleaved re/im rows (Nyquist handled rank-1)

__device__ __forceinline__ void gld16(const bf16* g, bf16* l) {
  __builtin_amdgcn_global_load_lds((const __attribute__((address_space(1))) void*)g,
                                   (__attribute__((address_space(3))) void*)l, 16, 0, 0);
}

#define MEMFENCE asm volatile("" ::: "memory")
#define BAR() do { MEMFENCE; __builtin_amdgcn_s_barrier(); MEMFENCE; } while (0)

__device__ __forceinline__ float fsin_rev(float rev) {
  float s; asm("v_sin_f32 %0, %1" : "=v"(s) : "v"(rev)); return s;
}
__device__ __forceinline__ float fcos_rev(float rev) {
  float c; asm("v_cos_f32 %0, %1" : "=v"(c) : "v"(rev)); return c;
}

// Stage one 128x64 bf16 half-tile global->LDS, pre-swizzled source (slot ^= row&7)
__device__ __forceinline__ void stage_half(const bf16* g, int ldk, bf16* ldsbase,
                                           int wave, int lane) {
  const int r8 = lane >> 3;
  const int sc = ((lane & 7) ^ r8) * 8;
  #pragma unroll
  for (int q = 0; q < 2; ++q) {
    const int c = wave * 2 + q;
    gld16(g + (size_t)(c * 8 + r8) * ldk + sc, ldsbase + c * 512);
  }
}

// swizzled LDS fragment read: 16B at slot (kk*4+l4)^(row&7)
__device__ __forceinline__ s16x8 ldfrag(const bf16* buf, int row, int kk, int l4) {
  return *(const s16x8*)(buf + row * 64 + (((kk * 4 + l4) ^ (row & 7)) * 8));
}

// -------- transpose + cast->bf16: out[c][r] = bf16(in[r][c]), batched over z
__global__ __launch_bounds__(256) void transpose_cast(
    const float* __restrict__ in, bf16* __restrict__ out, int R, int C) {
  __shared__ float tile[32][33];
  const size_t bo = (size_t)blockIdx.z * R * C;
  const float* inb = in + bo;
  bf16* outb = out + bo;
  int c0 = blockIdx.x * 32, r0 = blockIdx.y * 32;
  int tx = threadIdx.x & 31, ty = threadIdx.x >> 5;
  #pragma unroll
  for (int i = 0; i < 32; i += 8)
    tile[ty + i][tx] = inb[(size_t)(r0 + ty + i) * C + (c0 + tx)];
  __syncthreads();
  #pragma unroll
  for (int i = 0; i < 32; i += 8)
    outb[(size_t)(c0 + ty + i) * R + (r0 + tx)] = __float2bfloat16(tile[tx][ty + i]);
}

// -------- Auf = bf16(P0 + P1) (two bf16 half-K partials)
__global__ __launch_bounds__(256) void add2_cast(
    const bf16* __restrict__ P, bf16* __restrict__ out) {
  size_t i = ((size_t)blockIdx.x * 256 + threadIdx.x) * 8;
  const size_t MN = (size_t)MR * DDIM;
  s16x8 a = *(const s16x8*)(P + i);
  s16x8 b = *(const s16x8*)(P + i + MN);
  bf16 o[8];
  #pragma unroll
  for (int e = 0; e < 8; ++e) {
    float fa = __uint_as_float((unsigned)(unsigned short)a[e] << 16);
    float fb = __uint_as_float((unsigned)(unsigned short)b[e] << 16);
    o[e] = __float2bfloat16(fa + fb);
  }
  *(s16x8*)(out + i) = *(const s16x8*)o;
}

// -------- Ybt[c][r] = bf16(sum_jg Slot[(jg,nt(c))][r][c&255]); slots [8192][256] f32
__global__ __launch_bounds__(256) void tr_reduce4(
    const float* __restrict__ S, bf16* __restrict__ out) {
  __shared__ float tile[32][33];
  int c0 = blockIdx.x * 32, r0 = blockIdx.y * 32;
  int tx = threadIdx.x & 31, ty = threadIdx.x >> 5;
  const int nt = c0 >> 8;
  const int scl = (c0 & 255) + tx;
  const size_t SB = (size_t)MR * 256;
  #pragma unroll
  for (int i = 0; i < 32; i += 8) {
    size_t ro = (size_t)(r0 + ty + i) * 256 + scl;
    tile[ty + i][tx] = S[(0 * 2 + nt) * SB + ro] + S[(1 * 2 + nt) * SB + ro] +
                       S[(2 * 2 + nt) * SB + ro] + S[(3 * 2 + nt) * SB + ro];
  }
  __syncthreads();
  #pragma unroll
  for (int i = 0; i < 32; i += 8)
    out[(size_t)(c0 + ty + i) * MR + (r0 + tx)] = __float2bfloat16(tile[tx][ty + i]);
}

// -------- y = sum of 4 f32 partials + (-1)^l * vnyq[o] / NFFT
__global__ __launch_bounds__(256) void reduce4y(
    const float* __restrict__ P, const float* __restrict__ vnyq,
    float* __restrict__ y) {
  size_t i = ((size_t)blockIdx.x * 256 + threadIdx.x) * 4;
  const size_t MN = (size_t)LSEQ * DDIM;
  int l = (int)(i >> 9), o = (int)(i & 511);
  f32x4 a = *(const f32x4*)(P + i);
  f32x4 b = *(const f32x4*)(P + i + MN);
  f32x4 c = *(const f32x4*)(P + i + 2 * MN);
  f32x4 d = *(const f32x4*)(P + i + 3 * MN);
  f32x4 v = *(const f32x4*)(vnyq + o);
  float sg = (l & 1) ? -(1.f / NFFT) : (1.f / NFFT);
  f32x4 r = a + b + c + d;
  r[0] += sg * v[0]; r[1] += sg * v[1]; r[2] += sg * v[2]; r[3] += sg * v[3];
  *(f32x4*)(y + i) = r;
}

// -------- forward-DFT matrix rows 0..8191: W[2f][t]=cos, W[2f+1][t]=-sin
__global__ __launch_bounds__(256) void gen_w(bf16* __restrict__ W) {
  int r = blockIdx.y;
  int t0 = (blockIdx.x * 256 + threadIdx.x) * 8;
  int f = r >> 1;
  bool odd = r & 1;
  bf16 o[8];
  #pragma unroll
  for (int i = 0; i < 8; ++i) {
    int m = (f * (t0 + i)) & (NFFT - 1);
    float rev = (float)m * (1.f / NFFT);
    float v = odd ? -fsin_rev(rev) : fcos_rev(rev);
    o[i] = __float2bfloat16(v);
  }
  *(s16x8*)(W + (size_t)r * LSEQ + t0) = *(const s16x8*)o;
}

// -------- inverse-DFT matrix [4096][8192]: Cinv[l][2f]=wf/N*cos, [2f+1]=-wf/N*sin
__global__ __launch_bounds__(256) void gen_cinv(bf16* __restrict__ Cinv) {
  int l = blockIdx.y;
  int r0 = (blockIdx.x * 256 + threadIdx.x) * 8;
  bf16 o[8];
  #pragma unroll
  for (int p = 0; p < 4; ++p) {
    int f = (r0 >> 1) + p;
    int m = (f * l) & (NFFT - 1);
    float rev = (float)m * (1.f / NFFT);
    float sc = ((f == 0) ? 1.f : 2.f) * (1.f / NFFT);
    o[2 * p] = __float2bfloat16(sc * fcos_rev(rev));
    o[2 * p + 1] = __float2bfloat16(-sc * fsin_rev(rev));
  }
  *(s16x8*)(Cinv + (size_t)l * MR + r0) = *(const s16x8*)o;
}

// -------- Pf[f][k][re,im] f32, f in [0,4096]; 2 f per block (phi reads amortized)
__global__ __launch_bounds__(256) void compute_pf(
    const float* __restrict__ phi, float* __restrict__ Pf) {
  int f0 = blockIdx.x * 2;
  int tid = threadIdx.x;
  int lane = tid & 63, wave = tid >> 6;
  float pre[2][KFLT], pim[2][KFLT];
  #pragma unroll
  for (int ff = 0; ff < 2; ++ff)
    #pragma unroll
    for (int k = 0; k < KFLT; ++k) { pre[ff][k] = 0.f; pim[ff][k] = 0.f; }
  for (int cch = 0; cch < LSEQ / 256; ++cch) {
    int t = cch * 256 + tid;
    const float4* pv = (const float4*)(phi + (size_t)t * KFLT);
    float4 v0 = pv[0], v1 = pv[1], v2 = pv[2], v3 = pv[3], v4 = pv[4], v5 = pv[5];
    float pr[KFLT] = {v0.x, v0.y, v0.z, v0.w, v1.x, v1.y, v1.z, v1.w,
                      v2.x, v2.y, v2.z, v2.w, v3.x, v3.y, v3.z, v3.w,
                      v4.x, v4.y, v4.z, v4.w, v5.x, v5.y, v5.z, v5.w};
    #pragma unroll
    for (int ff = 0; ff < 2; ++ff) {
      int m = ((f0 + ff) * t) & (NFFT - 1);
      float rev = (float)m * (1.f / NFFT);
      float s = fsin_rev(rev), c = fcos_rev(rev);
      #pragma unroll
      for (int k = 0; k < KFLT; ++k) {
        pre[ff][k] += pr[k] * c;
        pim[ff][k] -= pr[k] * s;
      }
    }
  }
  __shared__ float red[4][2][2 * KFLT];
  #pragma unroll
  for (int ff = 0; ff < 2; ++ff)
    #pragma unroll
    for (int k = 0; k < KFLT; ++k) {
      float r = pre[ff][k], i2 = pim[ff][k];
      #pragma unroll
      for (int off = 32; off > 0; off >>= 1) {
        r += __shfl_down(r, off, 64);
        i2 += __shfl_down(i2, off, 64);
      }
      if (lane == 0) { red[wave][ff][2 * k] = r; red[wave][ff][2 * k + 1] = i2; }
    }
  __syncthreads();
  if (tid < 96) {
    int ff = tid / 48, q = tid % 48;
    int f = f0 + ff;
    if (f <= NFFT / 2)
      Pf[(size_t)f * 48 + q] =
          red[0][ff][q] + red[1][ff][q] + red[2][ff][q] + red[3][ff][q];
  }
}

// -------- Pw[j][f][re,im], f in [0,4096); also wnyq[48]
__global__ __launch_bounds__(256) void build_pw(
    const float* __restrict__ Pf, float* __restrict__ Pw, float* __restrict__ wnyq) {
  int idx = blockIdx.x * 256 + threadIdx.x;
  int j = idx >> 12, f = idx & 4095;
  float re, im;
  if (j < KFLT) {
    re = Pf[(size_t)f * 48 + j * 2];
    im = Pf[(size_t)f * 48 + j * 2 + 1];
  } else {
    int k = j - KFLT, g = NFFT / 2 - f;
    re = Pf[(size_t)g * 48 + k * 2];
    im = -Pf[(size_t)g * 48 + k * 2 + 1];
  }
  Pw[(size_t)idx * 2] = re;
  Pw[(size_t)idx * 2 + 1] = im;
  if (idx < 48)
    wnyq[idx] = (idx < KFLT) ? Pf[(size_t)(NFFT / 2) * 48 + idx * 2]
                             : Pf[(idx - KFLT) * 2];
}

// -------- Unyq[d] += partial sum_t (-1)^t u[t][d]  (coalesced, 128 blocks)
__global__ __launch_bounds__(256) void nyq_u(
    const float* __restrict__ u, float* __restrict__ Unyq) {
  int d = blockIdx.x * 256 + threadIdx.x;
  int t0 = blockIdx.y * 64;
  float acc = 0.f;
  for (int t = t0; t < t0 + 64; t += 2)
    acc += u[(size_t)t * DDIM + d] - u[(size_t)(t + 1) * DDIM + d];
  atomicAdd(&Unyq[d], acc);
}

// -------- vnyq[o] += wnyq[j] * sum_d Unyq[d]*Mt[j][o][d]   (grid 48 x 4)
__global__ __launch_bounds__(256) void vnyq_k(
    const bf16* __restrict__ Mt, const float* __restrict__ Unyq,
    const float* __restrict__ wnyq, float* __restrict__ vnyq) {
  __shared__ float us[DDIM];
  int j = blockIdx.x, tid = threadIdx.x;
  us[tid] = Unyq[tid];
  us[tid + 256] = Unyq[tid + 256];
  __syncthreads();
  float w = wnyq[j];
  int o = blockIdx.y * 128 + (tid >> 1);
  int dh = (tid & 1) * 256;
  const bf16* row = Mt + ((size_t)j * DDIM + o) * DDIM + dh;
  float acc = 0.f;
  for (int d0 = 0; d0 < 256; d0 += 8) {
    s16x8 v = *(const s16x8*)(row + d0);
    #pragma unroll
    for (int e = 0; e < 8; ++e)
      acc += us[dh + d0 + e] * __uint_as_float((unsigned)(unsigned short)v[e] << 16);
  }
  acc += __shfl_xor(acc, 1, 64);
  if ((tid & 1) == 0) atomicAdd(&vnyq[o], w * acc);
}

// ======== direct GEMM (G1/G3): C = A[M,K] @ Bt[N,K]^T, BM=128 BN=256 BK=64,
// 8 waves 2x4 (wave 64x64), exact-cover 256 blocks, 3-deep LDS + counted vmcnt(6).
template <int STORE>
__global__ __launch_bounds__(512, 2) void gemmD(
    const bf16* __restrict__ A, const bf16* __restrict__ Bt, int ldk,
    bf16* __restrict__ Obf, float* __restrict__ Of) {
  __shared__ bf16 sA[3 * 128 * 64];
  __shared__ bf16 sB[3 * 256 * 64];

  const int lin = blockIdx.x;
  const int wid = (lin & 7) * 32 + (lin >> 3);

  int mt, nt, kt0, nkt, ks;
  if constexpr (STORE == 0) {
    ks = wid >> 7; int rem = wid & 127; mt = rem >> 1; nt = rem & 1;
    kt0 = ks * 32; nkt = 32;
  } else {
    ks = wid >> 6; int rem = wid & 63; mt = rem >> 1; nt = rem & 1;
    kt0 = ks * 32; nkt = 32;
  }

  const int tid = threadIdx.x, lane = tid & 63, wave = tid >> 6;
  const int l15 = lane & 15, l4 = lane >> 4;
  const int wr = wave >> 2, wc = wave & 3;
  const int mtile = mt * 128, ntile = nt * 256;
  const bf16* Ab = A + (size_t)mtile * ldk;
  const bf16* Bb = Bt + (size_t)ntile * ldk;

  f32x4 acc[4][4];
  #pragma unroll
  for (int m = 0; m < 4; ++m)
    #pragma unroll
    for (int n = 0; n < 4; ++n) acc[m][n] = f32x4{0.f, 0.f, 0.f, 0.f};

  auto stage = [&](int t, int buf) {
    const size_t ko = (size_t)(kt0 + t) * 64;
    stage_half(Ab + ko, ldk, sA + buf * (128 * 64), wave, lane);
    stage_half(Bb + ko, ldk, sB + buf * (256 * 64), wave, lane);
    stage_half(Bb + (size_t)128 * ldk + ko, ldk, sB + buf * (256 * 64) + 128 * 64,
               wave, lane);
  };

  stage(0, 0);
  stage(1, 1);
  asm volatile("s_waitcnt vmcnt(6)" ::: "memory");   // tile 0 landed, tile 1 in flight
  BAR();

  for (int t = 0; t < nkt; ++t) {
    const int buf = t % 3;
    const bf16* bA = sA + buf * (128 * 64);
    const bf16* bB = sB + buf * (256 * 64);
    const bool i2 = (t + 2 < nkt);

    s16x8 afr[4][2], bfr[4][2];
    #pragma unroll
    for (int n = 0; n < 4; ++n)
      #pragma unroll
      for (int kk = 0; kk < 2; ++kk)
        bfr[n][kk] = ldfrag(bB, wc * 64 + n * 16 + l15, kk, l4);
    #pragma unroll
    for (int m = 0; m < 4; ++m)
      #pragma unroll
      for (int kk = 0; kk < 2; ++kk)
        afr[m][kk] = ldfrag(bA, wr * 64 + m * 16 + l15, kk, l4);

    if (i2) stage(t + 2, (t + 2) % 3);

    __builtin_amdgcn_s_setprio(1);
    #pragma unroll
    for (int m = 0; m < 4; ++m)
      #pragma unroll
      for (int n = 0; n < 4; ++n)
        #pragma unroll
        for (int kk = 0; kk < 2; ++kk)
          acc[m][n] = __builtin_amdgcn_mfma_f32_16x16x32_bf16(
              afr[m][kk], bfr[n][kk], acc[m][n], 0, 0, 0);
    __builtin_amdgcn_s_setprio(0);

    if (i2) { asm volatile("s_waitcnt vmcnt(6)" ::: "memory"); }
    else    { asm volatile("s_waitcnt vmcnt(0)" ::: "memory"); }
    BAR();
  }

  #pragma unroll
  for (int m = 0; m < 4; ++m)
    #pragma unroll
    for (int n = 0; n < 4; ++n)
      #pragma unroll
      for (int e = 0; e < 4; ++e) {
        int row = mtile + wr * 64 + m * 16 + l4 * 4 + e;
        int col = ntile + wc * 64 + n * 16 + l15;
        if constexpr (STORE == 0)
          Obf[(size_t)ks * MR * DDIM + (size_t)row * DDIM + col] =
              __float2bfloat16(acc[m][n][e]);
        else
          Of[(size_t)ks * LSEQ * DDIM + (size_t)row * DDIM + col] = acc[m][n][e];
      }
}

// ======== G2: Slot[(jg,nt)] = sum_{j in jg} Pw[j] .* (Auf @ Mt_j^T), pre-weighted A.
// L2-RESIDENT A PARTITION: XCD slot q encodes (jg = q>>1, mhalf = q&1); block pos
// encodes (nt = pos>>4, mt = mhalf*16 + (pos&15)). Per-XCD A working set =
// 16 tiles x 256KB = 4.19MB ~ L2; each A-tile read by both nt-blocks in the SAME
// XCD. Deep pipeline (R6-best): A-regs + B-gld16 issued 2 units ahead; sA 2-deep,
// sB 3-deep (160KB); one barrier + counted vmcnt(10) per unit.
struct ARegs { int4 a[4]; float2 w[2]; };

__global__ __launch_bounds__(512, 2) void gemmW(
    const bf16* __restrict__ Auf, const bf16* __restrict__ Mt,
    const float* __restrict__ Pw, float* __restrict__ Slots) {
  __shared__ bf16 sA[2 * 256 * 64];
  __shared__ bf16 sB[3 * 256 * 64];

  const int lin = blockIdx.x;
  const int q = lin & 7;                    // XCD slot (round-robin dispatch)
  const int pos = lin >> 3;                 // 0..31 within XCD
  const int jg = q >> 1, mhalf = q & 1;
  const int nt = pos >> 4;
  const int mt = mhalf * 16 + (pos & 15);

  const int tid = threadIdx.x, lane = tid & 63, wave = tid >> 6;
  const int l15 = lane & 15, l4 = lane >> 4;
  const int wr = wave >> 2, wc = wave & 3;  // 2x4 waves, wave 128x64
  const int r8 = lane >> 3, c8 = lane & 7;

  float* dst = Slots + (size_t)(jg * 2 + nt) * ((size_t)MR * 256);

  f32x4 acc[8][4];
  #pragma unroll
  for (int m = 0; m < 8; ++m)
    #pragma unroll
    for (int n = 0; n < 4; ++n) acc[m][n] = f32x4{0.f, 0.f, 0.f, 0.f};

  auto J  = [&](int s) { return jg * 12 + (s >> 3); };
  auto KT = [&](int s) { return s & 7; };

  // per-lane row-pair A load (4 int4 + 2 float2 = 6 vmem)
  auto issueA = [&](int j, int kt, ARegs& r) {
    #pragma unroll
    for (int qq = 0; qq < 2; ++qq) {
      int row_e = wave * 32 + 2 * (qq * 8 + r8);
      int rg = mt * 256 + row_e;
      const bf16* p = Auf + (size_t)rg * DDIM + kt * 64 + c8 * 8;
      r.a[2 * qq]     = *(const int4*)p;
      r.a[2 * qq + 1] = *(const int4*)(p + DDIM);
      r.w[qq] = *(const float2*)(Pw + ((size_t)j * 4096 + (rg >> 1)) * 2);
    }
  };
  // complex mix + swizzled ds_write (4 x b128)
  auto writeA = [&](bf16* db, const ARegs& r) {
    #pragma unroll
    for (int qq = 0; qq < 2; ++qq) {
      int row_e = wave * 32 + 2 * (qq * 8 + r8);
      union { int4 i; unsigned short u[8]; } ae, ao;
      ae.i = r.a[2 * qq]; ao.i = r.a[2 * qq + 1];
      bf16 oe[8], oo[8];
      #pragma unroll
      for (int e = 0; e < 8; ++e) {
        float fe = __uint_as_float((unsigned)ae.u[e] << 16);
        float fo = __uint_as_float((unsigned)ao.u[e] << 16);
        oe[e] = __float2bfloat16(r.w[qq].x * fe - r.w[qq].y * fo);
        oo[e] = __float2bfloat16(r.w[qq].x * fo + r.w[qq].y * fe);
      }
      *(s16x8*)(db + row_e * 64 + ((c8 ^ (row_e & 7)) * 8)) = *(const s16x8*)oe;
      *(s16x8*)(db + (row_e + 1) * 64 + ((c8 ^ ((row_e + 1) & 7)) * 8)) =
          *(const s16x8*)oo;
    }
  };
  auto stageB = [&](int j, int kt, bf16* db) {
    const bf16* bb = Mt + (size_t)j * (DDIM * DDIM) + (size_t)(nt * 256) * DDIM + kt * 64;
    stage_half(bb, DDIM, db, wave, lane);
    stage_half(bb + (size_t)128 * DDIM, DDIM, db + 128 * 64, wave, lane);
  };

  ARegs rA, rB_;

  // ---- prologue: A'(0) written; B(0) landed; unit-1 issues in flight
  {
    ARegs t0;
    issueA(J(0), KT(0), t0);                          // 6 vmem
    stageB(J(0), KT(0), sB);                          // 4 gld16
    asm volatile("s_waitcnt vmcnt(4)" ::: "memory");  // t0 regs ready
    writeA(sA, t0);
    issueA(J(1), KT(1), rA);                          // 6
    stageB(J(1), KT(1), sB + 256 * 64);               // 4
    asm volatile("s_waitcnt vmcnt(10)" ::: "memory"); // B(0) landed
    asm volatile("s_waitcnt lgkmcnt(0)" ::: "memory");
    BAR();
  }

  auto unit = [&](int s, ARegs& cur, ARegs& nxt) {
    const bf16* bA = sA + (s & 1) * (256 * 64);
    const bf16* bB = sB + (s % 3) * (256 * 64);
    const bool i2 = (s + 2 < 96);

    s16x8 bfr[4][2], afr[4][2];
    #pragma unroll
    for (int n = 0; n < 4; ++n)
      #pragma unroll
      for (int kk = 0; kk < 2; ++kk)
        bfr[n][kk] = ldfrag(bB, wc * 64 + n * 16 + l15, kk, l4);
    #pragma unroll
    for (int m = 0; m < 4; ++m)
      #pragma unroll
      for (int kk = 0; kk < 2; ++kk)
        afr[m][kk] = ldfrag(bA, wr * 128 + m * 16 + l15, kk, l4);

    if (i2) {
      issueA(J(s + 2), KT(s + 2), nxt);               // 6 vmem
      stageB(J(s + 2), KT(s + 2), sB + ((s + 2) % 3) * (256 * 64));  // 4 gld16
    }

    __builtin_amdgcn_s_setprio(1);
    #pragma unroll
    for (int m = 0; m < 4; ++m)
      #pragma unroll
      for (int n = 0; n < 4; ++n)
        #pragma unroll
        for (int kk = 0; kk < 2; ++kk)
          acc[m][n] = __builtin_amdgcn_mfma_f32_16x16x32_bf16(
              afr[m][kk], bfr[n][kk], acc[m][n], 0, 0, 0);
    __builtin_amdgcn_s_setprio(0);

    #pragma unroll
    for (int m = 0; m < 4; ++m)
      #pragma unroll
      for (int kk = 0; kk < 2; ++kk)
        afr[m][kk] = ldfrag(bA, wr * 128 + 64 + m * 16 + l15, kk, l4);

    if (s + 1 < 96) {
      if (i2) { asm volatile("s_waitcnt vmcnt(10)" ::: "memory"); }
      else    { asm volatile("s_waitcnt vmcnt(0)" ::: "memory"); }
      writeA(sA + ((s + 1) & 1) * (256 * 64), cur);   // A'(s+1)
    }

    __builtin_amdgcn_s_setprio(1);
    #pragma unroll
    for (int m = 0; m < 4; ++m)
      #pragma unroll
      for (int n = 0; n < 4; ++n)
        #pragma unroll
        for (int kk = 0; kk < 2; ++kk)
          acc[4 + m][n] = __builtin_amdgcn_mfma_f32_16x16x32_bf16(
              afr[m][kk], bfr[n][kk], acc[4 + m][n], 0, 0, 0);
    __builtin_amdgcn_s_setprio(0);

    asm volatile("s_waitcnt lgkmcnt(0)" ::: "memory");
    BAR();
  };

  for (int sp = 0; sp < 48; ++sp) {
    unit(2 * sp,     rA, rB_);
    unit(2 * sp + 1, rB_, rA);
  }

  // single flush into the block's private (mt, nt) slot region
  #pragma unroll
  for (int m = 0; m < 8; ++m)
    #pragma unroll
    for (int n = 0; n < 4; ++n)
      #pragma unroll
      for (int e = 0; e < 4; ++e) {
        int row = mt * 256 + wr * 128 + (m & 3) * 16 + (m >> 2) * 64 + l4 * 4 + e;
        int col = wc * 64 + n * 16 + l15;
        dst[(size_t)row * 256 + col] = acc[m][n][e];
      }
}

// ---------------- workspace layout (bytes) ----------------
#define WS_W     0ULL                    // 8192x4096 bf16 = 67,108,864 (W / G2 slots / Cinv)
#define WS_AUF   67108864ULL             // 8192x512 bf16 = 8,388,608 (later G3P start)
#define WS_UT    75497472ULL             // 512x4096 bf16 = 4,194,304
#define WS_MT    79691776ULL             // 48x512x512 bf16 = 25,165,824
#define WS_PF    104857600ULL            // 4097x48 f32
#define WS_PW    105644288ULL            // 48x4096x2 f32 = 1,572,864
#define WS_WNYQ  107217152ULL            // 48 f32
#define WS_UNYQ  107217408ULL            // 512 f32
#define WS_VNYQ  107219456ULL            // 512 f32
#define WS_YBT   107221504ULL            // 512x8192 bf16 = 8,388,608
#define WS_G1P   115610112ULL            // 2 x 8192x512 bf16 = 16,777,216
#define WS_TOTAL 132387328ULL
// G3 partials: 4 x 4096x512 f32 = 33,554,432 at WS_AUF (Auf/uT/Mt dead by G3)

extern "C" void kernel_launch(void* const* d_in, const int* in_sizes, int n_in,
                              void* d_out, int out_size, void* d_ws, size_t ws_size,
                              hipStream_t stream) {
  const float* u   = (const float*)d_in[0];   // [4096, 512]
  const float* phi = (const float*)d_in[1];   // [4096, 24]
  const float* Mp  = (const float*)d_in[2];   // [24, 512, 512]
  const float* Mm  = (const float*)d_in[3];   // [24, 512, 512]
  float* y = (float*)d_out;                   // [4096, 512]

  if (ws_size < WS_TOTAL) return;             // loud failure: output stays zero

  char* ws = (char*)d_ws;
  bf16*  W    = (bf16*)(ws + WS_W);
  float* Slots= (float*)(ws + WS_W);          // G2 slots overlay (W dead after G1)
  bf16*  Auf  = (bf16*)(ws + WS_AUF);
  bf16*  uT   = (bf16*)(ws + WS_UT);
  bf16*  Mt   = (bf16*)(ws + WS_MT);
  float* Pf   = (float*)(ws + WS_PF);
  float* Pw   = (float*)(ws + WS_PW);
  float* wny  = (float*)(ws + WS_WNYQ);
  float* Uny  = (float*)(ws + WS_UNYQ);
  float* vny  = (float*)(ws + WS_VNYQ);
  bf16*  Ybt  = (bf16*)(ws + WS_YBT);
  bf16*  G1P  = (bf16*)(ws + WS_G1P);
  float* G3P  = (float*)(ws + WS_AUF);        // G3 partials overlay

  // prologue
  transpose_cast<<<dim3(16, 128, 1), 256, 0, stream>>>(u, uT, LSEQ, DDIM);
  transpose_cast<<<dim3(16, 16, 24), 256, 0, stream>>>(Mp, Mt, DDIM, DDIM);
  transpose_cast<<<dim3(16, 16, 24), 256, 0, stream>>>(Mm, Mt + (size_t)24 * DDIM * DDIM,
                                                       DDIM, DDIM);
  gen_w<<<dim3(2, MR), 256, 0, stream>>>(W);
  compute_pf<<<dim3(2049), 256, 0, stream>>>(phi, Pf);
  build_pw<<<dim3(48 * 4096 / 256), 256, 0, stream>>>(Pf, Pw, wny);
  hipMemsetAsync(Uny, 0, DDIM * sizeof(float), stream);
  nyq_u<<<dim3(2, 64), 256, 0, stream>>>(u, Uny);

  // G1: Auf = bf16(Wdft @ u), 256 blocks, ks2 bf16 partials + add-cast
  gemmD<0><<<256, 512, 0, stream>>>(W, uT, LSEQ, G1P, nullptr);
  add2_cast<<<dim3(MR * DDIM / 2048), 256, 0, stream>>>(G1P, Auf);

  // G2: 8 XCD-combo slots in W region (full coverage, no memset)
  gemmW<<<256, 512, 0, stream>>>(Auf, Mt, Pw, Slots);

  // Ybt = bf16((sum of 4 jg-slots)^T); Nyquist vector (needs Mt) before G3
  tr_reduce4<<<dim3(16, 256), 256, 0, stream>>>(Slots, Ybt);
  hipMemsetAsync(vny, 0, DDIM * sizeof(float), stream);
  vnyq_k<<<dim3(48, 4), 256, 0, stream>>>(Mt, Uny, wny, vny);

  // G3: y = Cinv @ Ysum via 4 f32 ksplit partials + fused Nyquist rank-1 reduce
  gen_cinv<<<dim3(4, LSEQ), 256, 0, stream>>>(W);
  gemmD<1><<<256, 512, 0, stream>>>(W, Ybt, MR, nullptr, G3P);
  reduce4y<<<dim3(LSEQ * DDIM / 1024), 256, 0, stream>>>(G3P, vny, y);
}

// Round 10
// 488.798 us; speedup vs baseline: 1.1515x; 1.0281x over previous
//
#include <hip/hip_runtime.h>
#include <hip/hip_bf16.h>
#include <cstdint>
#include <cstddef>

using bf16 = __hip_bfloat16;

typedef __attribute__((ext_vector_type(4))) float f32x4;
typedef __attribute__((ext_vector_type(8))) short s16x8;

#define LSEQ 4096
#define DDIM 512
#define KFLT 24
#define NFFT 8192
#define MR 8192              // 2*4096 interleaved re/im rows (Nyquist handled rank-1)

__device__ __forceinline__ void gld16(const bf16* g, bf16* l) {
  __builtin_amdgcn_global_load_lds((const __attribute__((address_space(1))) void*)g,
                                   (__attribute__((address_space(3))) void*)l, 16, 0, 0);
}

#define MEMFENCE asm volatile("" ::: "memory")
#define BAR() do { MEMFENCE; __builtin_amdgcn_s_barrier(); MEMFENCE; } while (0)

__device__ __forceinline__ float fsin_rev(float rev) {
  float s; asm("v_sin_f32 %0, %1" : "=v"(s) : "v"(rev)); return s;
}
__device__ __forceinline__ float fcos_rev(float rev) {
  float c; asm("v_cos_f32 %0, %1" : "=v"(c) : "v"(rev)); return c;
}

// Stage one 128x64 bf16 half-tile global->LDS, pre-swizzled source (slot ^= row&7)
__device__ __forceinline__ void stage_half(const bf16* g, int ldk, bf16* ldsbase,
                                           int wave, int lane) {
  const int r8 = lane >> 3;
  const int sc = ((lane & 7) ^ r8) * 8;
  #pragma unroll
  for (int q = 0; q < 2; ++q) {
    const int c = wave * 2 + q;
    gld16(g + (size_t)(c * 8 + r8) * ldk + sc, ldsbase + c * 512);
  }
}

// swizzled LDS fragment read: 16B at slot (kk*4+l4)^(row&7)
__device__ __forceinline__ s16x8 ldfrag(const bf16* buf, int row, int kk, int l4) {
  return *(const s16x8*)(buf + row * 64 + (((kk * 4 + l4) ^ (row & 7)) * 8));
}

// -------- transpose + cast->bf16: out[c][r] = bf16(in[r][c]), batched over z
__global__ __launch_bounds__(256) void transpose_cast(
    const float* __restrict__ in, bf16* __restrict__ out, int R, int C) {
  __shared__ float tile[32][33];
  const size_t bo = (size_t)blockIdx.z * R * C;
  const float* inb = in + bo;
  bf16* outb = out + bo;
  int c0 = blockIdx.x * 32, r0 = blockIdx.y * 32;
  int tx = threadIdx.x & 31, ty = threadIdx.x >> 5;
  #pragma unroll
  for (int i = 0; i < 32; i += 8)
    tile[ty + i][tx] = inb[(size_t)(r0 + ty + i) * C + (c0 + tx)];
  __syncthreads();
  #pragma unroll
  for (int i = 0; i < 32; i += 8)
    outb[(size_t)(c0 + ty + i) * R + (r0 + tx)] = __float2bfloat16(tile[tx][ty + i]);
}

// -------- Auf = bf16(P0 + P1) (two bf16 half-K partials)
__global__ __launch_bounds__(256) void add2_cast(
    const bf16* __restrict__ P, bf16* __restrict__ out) {
  size_t i = ((size_t)blockIdx.x * 256 + threadIdx.x) * 8;
  const size_t MN = (size_t)MR * DDIM;
  s16x8 a = *(const s16x8*)(P + i);
  s16x8 b = *(const s16x8*)(P + i + MN);
  bf16 o[8];
  #pragma unroll
  for (int e = 0; e < 8; ++e) {
    float fa = __uint_as_float((unsigned)(unsigned short)a[e] << 16);
    float fb = __uint_as_float((unsigned)(unsigned short)b[e] << 16);
    o[e] = __float2bfloat16(fa + fb);
  }
  *(s16x8*)(out + i) = *(const s16x8*)o;
}

// -------- Ybt[c][r] = bf16(sum_jg Slot[(jg,nt(c))][r][c&255]); slots [8192][256] f32
__global__ __launch_bounds__(256) void tr_reduce4(
    const float* __restrict__ S, bf16* __restrict__ out) {
  __shared__ float tile[32][33];
  int c0 = blockIdx.x * 32, r0 = blockIdx.y * 32;
  int tx = threadIdx.x & 31, ty = threadIdx.x >> 5;
  const int nt = c0 >> 8;
  const int scl = (c0 & 255) + tx;
  const size_t SB = (size_t)MR * 256;
  #pragma unroll
  for (int i = 0; i < 32; i += 8) {
    size_t ro = (size_t)(r0 + ty + i) * 256 + scl;
    tile[ty + i][tx] = S[(0 * 2 + nt) * SB + ro] + S[(1 * 2 + nt) * SB + ro] +
                       S[(2 * 2 + nt) * SB + ro] + S[(3 * 2 + nt) * SB + ro];
  }
  __syncthreads();
  #pragma unroll
  for (int i = 0; i < 32; i += 8)
    out[(size_t)(c0 + ty + i) * MR + (r0 + tx)] = __float2bfloat16(tile[tx][ty + i]);
}

// -------- y = sum of 4 f32 partials + (-1)^l * vnyq[o] / NFFT
__global__ __launch_bounds__(256) void reduce4y(
    const float* __restrict__ P, const float* __restrict__ vnyq,
    float* __restrict__ y) {
  size_t i = ((size_t)blockIdx.x * 256 + threadIdx.x) * 4;
  const size_t MN = (size_t)LSEQ * DDIM;
  int l = (int)(i >> 9), o = (int)(i & 511);
  f32x4 a = *(const f32x4*)(P + i);
  f32x4 b = *(const f32x4*)(P + i + MN);
  f32x4 c = *(const f32x4*)(P + i + 2 * MN);
  f32x4 d = *(const f32x4*)(P + i + 3 * MN);
  f32x4 v = *(const f32x4*)(vnyq + o);
  float sg = (l & 1) ? -(1.f / NFFT) : (1.f / NFFT);
  f32x4 r = a + b + c + d;
  r[0] += sg * v[0]; r[1] += sg * v[1]; r[2] += sg * v[2]; r[3] += sg * v[3];
  *(f32x4*)(y + i) = r;
}

// -------- Pf[f][k][re,im] f32, f in [0,4096]; 2 f per block (phi reads amortized)
__global__ __launch_bounds__(256) void compute_pf(
    const float* __restrict__ phi, float* __restrict__ Pf) {
  int f0 = blockIdx.x * 2;
  int tid = threadIdx.x;
  int lane = tid & 63, wave = tid >> 6;
  float pre[2][KFLT], pim[2][KFLT];
  #pragma unroll
  for (int ff = 0; ff < 2; ++ff)
    #pragma unroll
    for (int k = 0; k < KFLT; ++k) { pre[ff][k] = 0.f; pim[ff][k] = 0.f; }
  for (int cch = 0; cch < LSEQ / 256; ++cch) {
    int t = cch * 256 + tid;
    const float4* pv = (const float4*)(phi + (size_t)t * KFLT);
    float4 v0 = pv[0], v1 = pv[1], v2 = pv[2], v3 = pv[3], v4 = pv[4], v5 = pv[5];
    float pr[KFLT] = {v0.x, v0.y, v0.z, v0.w, v1.x, v1.y, v1.z, v1.w,
                      v2.x, v2.y, v2.z, v2.w, v3.x, v3.y, v3.z, v3.w,
                      v4.x, v4.y, v4.z, v4.w, v5.x, v5.y, v5.z, v5.w};
    #pragma unroll
    for (int ff = 0; ff < 2; ++ff) {
      int m = ((f0 + ff) * t) & (NFFT - 1);
      float rev = (float)m * (1.f / NFFT);
      float s = fsin_rev(rev), c = fcos_rev(rev);
      #pragma unroll
      for (int k = 0; k < KFLT; ++k) {
        pre[ff][k] += pr[k] * c;
        pim[ff][k] -= pr[k] * s;
      }
    }
  }
  __shared__ float red[4][2][2 * KFLT];
  #pragma unroll
  for (int ff = 0; ff < 2; ++ff)
    #pragma unroll
    for (int k = 0; k < KFLT; ++k) {
      float r = pre[ff][k], i2 = pim[ff][k];
      #pragma unroll
      for (int off = 32; off > 0; off >>= 1) {
        r += __shfl_down(r, off, 64);
        i2 += __shfl_down(i2, off, 64);
      }
      if (lane == 0) { red[wave][ff][2 * k] = r; red[wave][ff][2 * k + 1] = i2; }
    }
  __syncthreads();
  if (tid < 96) {
    int ff = tid / 48, q = tid % 48;
    int f = f0 + ff;
    if (f <= NFFT / 2)
      Pf[(size_t)f * 48 + q] =
          red[0][ff][q] + red[1][ff][q] + red[2][ff][q] + red[3][ff][q];
  }
}

// -------- Pw[j][f][re,im], f in [0,4096); also wnyq[48]
__global__ __launch_bounds__(256) void build_pw(
    const float* __restrict__ Pf, float* __restrict__ Pw, float* __restrict__ wnyq) {
  int idx = blockIdx.x * 256 + threadIdx.x;
  int j = idx >> 12, f = idx & 4095;
  float re, im;
  if (j < KFLT) {
    re = Pf[(size_t)f * 48 + j * 2];
    im = Pf[(size_t)f * 48 + j * 2 + 1];
  } else {
    int k = j - KFLT, g = NFFT / 2 - f;
    re = Pf[(size_t)g * 48 + k * 2];
    im = -Pf[(size_t)g * 48 + k * 2 + 1];
  }
  Pw[(size_t)idx * 2] = re;
  Pw[(size_t)idx * 2 + 1] = im;
  if (idx < 48)
    wnyq[idx] = (idx < KFLT) ? Pf[(size_t)(NFFT / 2) * 48 + idx * 2]
                             : Pf[(idx - KFLT) * 2];
}

// -------- Unyq[d] += partial sum_t (-1)^t u[t][d]  (coalesced, 128 blocks)
__global__ __launch_bounds__(256) void nyq_u(
    const float* __restrict__ u, float* __restrict__ Unyq) {
  int d = blockIdx.x * 256 + threadIdx.x;
  int t0 = blockIdx.y * 64;
  float acc = 0.f;
  for (int t = t0; t < t0 + 64; t += 2)
    acc += u[(size_t)t * DDIM + d] - u[(size_t)(t + 1) * DDIM + d];
  atomicAdd(&Unyq[d], acc);
}

// -------- vnyq[o] += wnyq[j] * sum_d Unyq[d]*Mt[j][o][d]   (grid 48 x 4)
__global__ __launch_bounds__(256) void vnyq_k(
    const bf16* __restrict__ Mt, const float* __restrict__ Unyq,
    const float* __restrict__ wnyq, float* __restrict__ vnyq) {
  __shared__ float us[DDIM];
  int j = blockIdx.x, tid = threadIdx.x;
  us[tid] = Unyq[tid];
  us[tid + 256] = Unyq[tid + 256];
  __syncthreads();
  float w = wnyq[j];
  int o = blockIdx.y * 128 + (tid >> 1);
  int dh = (tid & 1) * 256;
  const bf16* row = Mt + ((size_t)j * DDIM + o) * DDIM + dh;
  float acc = 0.f;
  for (int d0 = 0; d0 < 256; d0 += 8) {
    s16x8 v = *(const s16x8*)(row + d0);
    #pragma unroll
    for (int e = 0; e < 8; ++e)
      acc += us[dh + d0 + e] * __uint_as_float((unsigned)(unsigned short)v[e] << 16);
  }
  acc += __shfl_xor(acc, 1, 64);
  if ((tid & 1) == 0) atomicAdd(&vnyq[o], w * acc);
}

// ======== GEN-GEMM (G1/G3): C = Wgen[M,K] @ Bt[N,K]^T, BM=128 BN=256 BK=64,
// 8 waves 2x4 (wave 64x64), exact-cover 256 blocks, 3-deep LDS.
// A-TILE IS GENERATED IN-KERNEL (trig), written to LDS with the reader's XOR
// swizzle — no W/Cinv matrix in HBM at all. B stages via gld16 (vmcnt(4) counted);
// A ds_writes covered by lgkmcnt(0) before the end-of-unit barrier.
// STORE 0 (G1, A = forward-DFT rows): ks2 x mt64 x nt2; bf16 partial store.
// STORE 1 (G3, A = inverse-DFT rows): ks4 x mt32 x nt2; f32 partial store.
template <int STORE>
__global__ __launch_bounds__(512, 2) void gemmG(
    const bf16* __restrict__ Bt, int ldk,
    bf16* __restrict__ Obf, float* __restrict__ Of) {
  __shared__ bf16 sA[3 * 128 * 64];
  __shared__ bf16 sB[3 * 256 * 64];

  const int lin = blockIdx.x;
  const int wid = (lin & 7) * 32 + (lin >> 3);

  int mt, nt, kt0, nkt, ks;
  if constexpr (STORE == 0) {
    ks = wid >> 7; int rem = wid & 127; mt = rem >> 1; nt = rem & 1;
    kt0 = ks * 32; nkt = 32;
  } else {
    ks = wid >> 6; int rem = wid & 63; mt = rem >> 1; nt = rem & 1;
    kt0 = ks * 32; nkt = 32;
  }

  const int tid = threadIdx.x, lane = tid & 63, wave = tid >> 6;
  const int l15 = lane & 15, l4 = lane >> 4;
  const int wr = wave >> 2, wc = wave & 3;
  const int r8 = lane >> 3, c8 = lane & 7;
  const int mtile = mt * 128, ntile = nt * 256;
  const bf16* Bb = Bt + (size_t)ntile * ldk;

  f32x4 acc[4][4];
  #pragma unroll
  for (int m = 0; m < 4; ++m)
    #pragma unroll
    for (int n = 0; n < 4; ++n) acc[m][n] = f32x4{0.f, 0.f, 0.f, 0.f};

  // generate this thread's 2x8 A elements for K-unit t into LDS buf (swizzled)
  auto genA = [&](int t, int buf) {
    const int kbase = (kt0 + t) * 64 + ((c8 ^ r8) * 8);   // pre-swizzled col base
    #pragma unroll
    for (int q = 0; q < 2; ++q) {
      const int c = wave * 2 + q;
      const int row = mtile + c * 8 + r8;
      bf16 o[8];
      if constexpr (STORE == 0) {
        const int f = row >> 1;
        const bool odd = row & 1;
        #pragma unroll
        for (int e = 0; e < 8; ++e) {
          int m = (f * (kbase + e)) & (NFFT - 1);
          float rev = (float)m * (1.f / NFFT);
          o[e] = __float2bfloat16(odd ? -fsin_rev(rev) : fcos_rev(rev));
        }
      } else {
        #pragma unroll
        for (int e = 0; e < 8; ++e) {
          int r = kbase + e;
          int f = r >> 1;
          int m = (f * row) & (NFFT - 1);
          float rev = (float)m * (1.f / NFFT);
          float sc2 = ((f == 0) ? 1.f : 2.f) * (1.f / NFFT);
          o[e] = __float2bfloat16((r & 1) ? -sc2 * fsin_rev(rev)
                                          : sc2 * fcos_rev(rev));
        }
      }
      *(s16x8*)(sA + buf * (128 * 64) + (c * 8 + r8) * 64 + c8 * 8) =
          *(const s16x8*)o;
    }
  };
  auto stageB = [&](int t, int buf) {
    const size_t ko = (size_t)(kt0 + t) * 64;
    stage_half(Bb + ko, ldk, sB + buf * (256 * 64), wave, lane);
    stage_half(Bb + (size_t)128 * ldk + ko, ldk, sB + buf * (256 * 64) + 128 * 64,
               wave, lane);
  };

  genA(0, 0);
  genA(1, 1);
  stageB(0, 0);
  stageB(1, 1);
  asm volatile("s_waitcnt vmcnt(4)" ::: "memory");   // B(0) landed, B(1) in flight
  asm volatile("s_waitcnt lgkmcnt(0)" ::: "memory"); // A(0),A(1) writes done
  BAR();

  for (int t = 0; t < nkt; ++t) {
    const int buf = t % 3;
    const bf16* bA = sA + buf * (128 * 64);
    const bf16* bB = sB + buf * (256 * 64);
    const bool i2 = (t + 2 < nkt);

    s16x8 afr[4][2], bfr[4][2];
    #pragma unroll
    for (int n = 0; n < 4; ++n)
      #pragma unroll
      for (int kk = 0; kk < 2; ++kk)
        bfr[n][kk] = ldfrag(bB, wc * 64 + n * 16 + l15, kk, l4);
    #pragma unroll
    for (int m = 0; m < 4; ++m)
      #pragma unroll
      for (int kk = 0; kk < 2; ++kk)
        afr[m][kk] = ldfrag(bA, wr * 64 + m * 16 + l15, kk, l4);

    if (i2) {
      genA(t + 2, (t + 2) % 3);
      stageB(t + 2, (t + 2) % 3);
    }

    __builtin_amdgcn_s_setprio(1);
    #pragma unroll
    for (int m = 0; m < 4; ++m)
      #pragma unroll
      for (int n = 0; n < 4; ++n)
        #pragma unroll
        for (int kk = 0; kk < 2; ++kk)
          acc[m][n] = __builtin_amdgcn_mfma_f32_16x16x32_bf16(
              afr[m][kk], bfr[n][kk], acc[m][n], 0, 0, 0);
    __builtin_amdgcn_s_setprio(0);

    if (i2) { asm volatile("s_waitcnt vmcnt(4)" ::: "memory"); }
    else    { asm volatile("s_waitcnt vmcnt(0)" ::: "memory"); }
    asm volatile("s_waitcnt lgkmcnt(0)" ::: "memory");
    BAR();
  }

  #pragma unroll
  for (int m = 0; m < 4; ++m)
    #pragma unroll
    for (int n = 0; n < 4; ++n)
      #pragma unroll
      for (int e = 0; e < 4; ++e) {
        int row = mtile + wr * 64 + m * 16 + l4 * 4 + e;
        int col = ntile + wc * 64 + n * 16 + l15;
        if constexpr (STORE == 0)
          Obf[(size_t)ks * MR * DDIM + (size_t)row * DDIM + col] =
              __float2bfloat16(acc[m][n][e]);
        else
          Of[(size_t)ks * LSEQ * DDIM + (size_t)row * DDIM + col] = acc[m][n][e];
      }
}

// ======== G2: Slot[(jg,nt)] = sum_{j in jg} Pw[j] .* (Auf @ Mt_j^T), pre-weighted A.
// L2-RESIDENT A PARTITION: XCD slot q encodes (jg = q>>1, mhalf = q&1); block pos
// encodes (nt = pos>>4, mt = mhalf*16 + (pos&15)). Deep pipeline: A-regs + B-gld16
// issued 2 units ahead; sA 2-deep, sB 3-deep (160KB); one barrier + vmcnt(10)/unit.
struct ARegs { int4 a[4]; float2 w[2]; };

__global__ __launch_bounds__(512, 2) void gemmW(
    const bf16* __restrict__ Auf, const bf16* __restrict__ Mt,
    const float* __restrict__ Pw, float* __restrict__ Slots) {
  __shared__ bf16 sA[2 * 256 * 64];
  __shared__ bf16 sB[3 * 256 * 64];

  const int lin = blockIdx.x;
  const int q = lin & 7;                    // XCD slot (round-robin dispatch)
  const int pos = lin >> 3;                 // 0..31 within XCD
  const int jg = q >> 1, mhalf = q & 1;
  const int nt = pos >> 4;
  const int mt = mhalf * 16 + (pos & 15);

  const int tid = threadIdx.x, lane = tid & 63, wave = tid >> 6;
  const int l15 = lane & 15, l4 = lane >> 4;
  const int wr = wave >> 2, wc = wave & 3;  // 2x4 waves, wave 128x64
  const int r8 = lane >> 3, c8 = lane & 7;

  float* dst = Slots + (size_t)(jg * 2 + nt) * ((size_t)MR * 256);

  f32x4 acc[8][4];
  #pragma unroll
  for (int m = 0; m < 8; ++m)
    #pragma unroll
    for (int n = 0; n < 4; ++n) acc[m][n] = f32x4{0.f, 0.f, 0.f, 0.f};

  auto J  = [&](int s) { return jg * 12 + (s >> 3); };
  auto KT = [&](int s) { return s & 7; };

  // per-lane row-pair A load (4 int4 + 2 float2 = 6 vmem)
  auto issueA = [&](int j, int kt, ARegs& r) {
    #pragma unroll
    for (int qq = 0; qq < 2; ++qq) {
      int row_e = wave * 32 + 2 * (qq * 8 + r8);
      int rg = mt * 256 + row_e;
      const bf16* p = Auf + (size_t)rg * DDIM + kt * 64 + c8 * 8;
      r.a[2 * qq]     = *(const int4*)p;
      r.a[2 * qq + 1] = *(const int4*)(p + DDIM);
      r.w[qq] = *(const float2*)(Pw + ((size_t)j * 4096 + (rg >> 1)) * 2);
    }
  };
  // complex mix + swizzled ds_write (4 x b128)
  auto writeA = [&](bf16* db, const ARegs& r) {
    #pragma unroll
    for (int qq = 0; qq < 2; ++qq) {
      int row_e = wave * 32 + 2 * (qq * 8 + r8);
      union { int4 i; unsigned short u[8]; } ae, ao;
      ae.i = r.a[2 * qq]; ao.i = r.a[2 * qq + 1];
      bf16 oe[8], oo[8];
      #pragma unroll
      for (int e = 0; e < 8; ++e) {
        float fe = __uint_as_float((unsigned)ae.u[e] << 16);
        float fo = __uint_as_float((unsigned)ao.u[e] << 16);
        oe[e] = __float2bfloat16(r.w[qq].x * fe - r.w[qq].y * fo);
        oo[e] = __float2bfloat16(r.w[qq].x * fo + r.w[qq].y * fe);
      }
      *(s16x8*)(db + row_e * 64 + ((c8 ^ (row_e & 7)) * 8)) = *(const s16x8*)oe;
      *(s16x8*)(db + (row_e + 1) * 64 + ((c8 ^ ((row_e + 1) & 7)) * 8)) =
          *(const s16x8*)oo;
    }
  };
  auto stageB = [&](int j, int kt, bf16* db) {
    const bf16* bb = Mt + (size_t)j * (DDIM * DDIM) + (size_t)(nt * 256) * DDIM + kt * 64;
    stage_half(bb, DDIM, db, wave, lane);
    stage_half(bb + (size_t)128 * DDIM, DDIM, db + 128 * 64, wave, lane);
  };

  ARegs rA, rB_;

  // ---- prologue: A'(0) written; B(0) landed; unit-1 issues in flight
  {
    ARegs t0;
    issueA(J(0), KT(0), t0);                          // 6 vmem
    stageB(J(0), KT(0), sB);                          // 4 gld16
    asm volatile("s_waitcnt vmcnt(4)" ::: "memory");  // t0 regs ready
    writeA(sA, t0);
    issueA(J(1), KT(1), rA);                          // 6
    stageB(J(1), KT(1), sB + 256 * 64);               // 4
    asm volatile("s_waitcnt vmcnt(10)" ::: "memory"); // B(0) landed
    asm volatile("s_waitcnt lgkmcnt(0)" ::: "memory");
    BAR();
  }

  auto unit = [&](int s, ARegs& cur, ARegs& nxt) {
    const bf16* bA = sA + (s & 1) * (256 * 64);
    const bf16* bB = sB + (s % 3) * (256 * 64);
    const bool i2 = (s + 2 < 96);

    s16x8 bfr[4][2], afr[4][2];
    #pragma unroll
    for (int n = 0; n < 4; ++n)
      #pragma unroll
      for (int kk = 0; kk < 2; ++kk)
        bfr[n][kk] = ldfrag(bB, wc * 64 + n * 16 + l15, kk, l4);
    #pragma unroll
    for (int m = 0; m < 4; ++m)
      #pragma unroll
      for (int kk = 0; kk < 2; ++kk)
        afr[m][kk] = ldfrag(bA, wr * 128 + m * 16 + l15, kk, l4);

    if (i2) {
      issueA(J(s + 2), KT(s + 2), nxt);               // 6 vmem
      stageB(J(s + 2), KT(s + 2), sB + ((s + 2) % 3) * (256 * 64));  // 4 gld16
    }

    __builtin_amdgcn_s_setprio(1);
    #pragma unroll
    for (int m = 0; m < 4; ++m)
      #pragma unroll
      for (int n = 0; n < 4; ++n)
        #pragma unroll
        for (int kk = 0; kk < 2; ++kk)
          acc[m][n] = __builtin_amdgcn_mfma_f32_16x16x32_bf16(
              afr[m][kk], bfr[n][kk], acc[m][n], 0, 0, 0);
    __builtin_amdgcn_s_setprio(0);

    #pragma unroll
    for (int m = 0; m < 4; ++m)
      #pragma unroll
      for (int kk = 0; kk < 2; ++kk)
        afr[m][kk] = ldfrag(bA, wr * 128 + 64 + m * 16 + l15, kk, l4);

    if (s + 1 < 96) {
      if (i2) { asm volatile("s_waitcnt vmcnt(10)" ::: "memory"); }
      else    { asm volatile("s_waitcnt vmcnt(0)" ::: "memory"); }
      writeA(sA + ((s + 1) & 1) * (256 * 64), cur);   // A'(s+1)
    }

    __builtin_amdgcn_s_setprio(1);
    #pragma unroll
    for (int m = 0; m < 4; ++m)
      #pragma unroll
      for (int n = 0; n < 4; ++n)
        #pragma unroll
        for (int kk = 0; kk < 2; ++kk)
          acc[4 + m][n] = __builtin_amdgcn_mfma_f32_16x16x32_bf16(
              afr[m][kk], bfr[n][kk], acc[4 + m][n], 0, 0, 0);
    __builtin_amdgcn_s_setprio(0);

    asm volatile("s_waitcnt lgkmcnt(0)" ::: "memory");
    BAR();
  };

  for (int sp = 0; sp < 48; ++sp) {
    unit(2 * sp,     rA, rB_);
    unit(2 * sp + 1, rB_, rA);
  }

  // single flush into the block's private (mt, nt) slot region
  #pragma unroll
  for (int m = 0; m < 8; ++m)
    #pragma unroll
    for (int n = 0; n < 4; ++n)
      #pragma unroll
      for (int e = 0; e < 4; ++e) {
        int row = mt * 256 + wr * 128 + (m & 3) * 16 + (m >> 2) * 64 + l4 * 4 + e;
        int col = wc * 64 + n * 16 + l15;
        dst[(size_t)row * 256 + col] = acc[m][n][e];
      }
}

// ---------------- workspace layout (bytes) ----------------
#define WS_W     0ULL                    // 67,108,864: G2 slots (8 x [8192][256] f32)
#define WS_AUF   67108864ULL             // 8192x512 bf16 = 8,388,608 (later G3P start)
#define WS_UT    75497472ULL             // 512x4096 bf16 = 4,194,304
#define WS_MT    79691776ULL             // 48x512x512 bf16 = 25,165,824
#define WS_PF    104857600ULL            // 4097x48 f32
#define WS_PW    105644288ULL            // 48x4096x2 f32 = 1,572,864
#define WS_WNYQ  107217152ULL            // 48 f32
#define WS_UNYQ  107217408ULL            // 512 f32
#define WS_VNYQ  107219456ULL            // 512 f32
#define WS_YBT   107221504ULL            // 512x8192 bf16 = 8,388,608
#define WS_G1P   115610112ULL            // 2 x 8192x512 bf16 = 16,777,216
#define WS_TOTAL 132387328ULL
// G3 partials: 4 x 4096x512 f32 = 33,554,432 at WS_AUF (Auf/uT/Mt dead by G3)

extern "C" void kernel_launch(void* const* d_in, const int* in_sizes, int n_in,
                              void* d_out, int out_size, void* d_ws, size_t ws_size,
                              hipStream_t stream) {
  const float* u   = (const float*)d_in[0];   // [4096, 512]
  const float* phi = (const float*)d_in[1];   // [4096, 24]
  const float* Mp  = (const float*)d_in[2];   // [24, 512, 512]
  const float* Mm  = (const float*)d_in[3];   // [24, 512, 512]
  float* y = (float*)d_out;                   // [4096, 512]

  if (ws_size < WS_TOTAL) return;             // loud failure: output stays zero

  char* ws = (char*)d_ws;
  float* Slots= (float*)(ws + WS_W);
  bf16*  Auf  = (bf16*)(ws + WS_AUF);
  bf16*  uT   = (bf16*)(ws + WS_UT);
  bf16*  Mt   = (bf16*)(ws + WS_MT);
  float* Pf   = (float*)(ws + WS_PF);
  float* Pw   = (float*)(ws + WS_PW);
  float* wny  = (float*)(ws + WS_WNYQ);
  float* Uny  = (float*)(ws + WS_UNYQ);
  float* vny  = (float*)(ws + WS_VNYQ);
  bf16*  Ybt  = (bf16*)(ws + WS_YBT);
  bf16*  G1P  = (bf16*)(ws + WS_G1P);
  float* G3P  = (float*)(ws + WS_AUF);        // G3 partials overlay

  // prologue (no W/Cinv materialization — generated inside gemmG)
  transpose_cast<<<dim3(16, 128, 1), 256, 0, stream>>>(u, uT, LSEQ, DDIM);
  transpose_cast<<<dim3(16, 16, 24), 256, 0, stream>>>(Mp, Mt, DDIM, DDIM);
  transpose_cast<<<dim3(16, 16, 24), 256, 0, stream>>>(Mm, Mt + (size_t)24 * DDIM * DDIM,
                                                       DDIM, DDIM);
  compute_pf<<<dim3(2049), 256, 0, stream>>>(phi, Pf);
  build_pw<<<dim3(48 * 4096 / 256), 256, 0, stream>>>(Pf, Pw, wny);
  hipMemsetAsync(Uny, 0, DDIM * sizeof(float), stream);
  nyq_u<<<dim3(2, 64), 256, 0, stream>>>(u, Uny);

  // G1: Auf = bf16(Wdft_gen @ u), 256 blocks, ks2 bf16 partials + add-cast
  gemmG<0><<<256, 512, 0, stream>>>(uT, LSEQ, G1P, nullptr);
  add2_cast<<<dim3(MR * DDIM / 2048), 256, 0, stream>>>(G1P, Auf);

  // G2: 8 XCD-combo slots (full coverage, no memset)
  gemmW<<<256, 512, 0, stream>>>(Auf, Mt, Pw, Slots);

  // Ybt = bf16((sum of 4 jg-slots)^T); Nyquist vector (needs Mt) before G3
  tr_reduce4<<<dim3(16, 256), 256, 0, stream>>>(Slots, Ybt);
  hipMemsetAsync(vny, 0, DDIM * sizeof(float), stream);
  vnyq_k<<<dim3(48, 4), 256, 0, stream>>>(Mt, Uny, wny, vny);

  // G3: y = Cinv_gen @ Ysum via 4 f32 ksplit partials + fused Nyquist reduce
  gemmG<1><<<256, 512, 0, stream>>>(Ybt, MR, nullptr, G3P);
  reduce4y<<<dim3(LSEQ * DDIM / 1024), 256, 0, stream>>>(G3P, vny, y);
}